// Round 7
// baseline (445.722 us; speedup 1.0000x reference)
//
#include <hip/hip_runtime.h>
#include <hip/hip_cooperative_groups.h>
#include <stdint.h>

namespace cg = cooperative_groups;

// D3 dispersion on MI355X (gfx950).
// R6 evidence: atomic-free bucket pipeline works (183us); remaining cost is
// dominated by harness ws-poison fills (45us, untouchable) + 11 dispatch
// boundaries. R7: single cooperative kernel, 512 blocks x 256 thr, grid.sync
// between phases; fixed-stride buckets (CAP=8192) eliminate count+scan.
// Reference semantics (established R2-R5): fp32 storage; np reference is fp32
// with FTZ in exp -> exceptional one-hot branch iff every masked gaussian
// arg < ln(2^-126) = -87.33654.

typedef unsigned short u16;
#define MAXZ 95
#define NREF 5
#define EXC_CUT -87.33654f
#define NB   512      // buckets == blocks
#define BSH  7        // log2 atoms per bucket
#define BSZ  128      // atoms per bucket
#define CAPSH 13      // log2 bucket capacity (8192; mean fill ~3.8K, ~70 sigma)
#define RC_TOTAL (MAXZ * MAXZ * 32)

__device__ __forceinline__ float switch_fn(float d) {
    if (d < 10.0f) return 1.0f;
    float x = (12.0f - d) * 0.5f;
    return ((6.0f * x - 15.0f) * x + 10.0f) * x * x * x;
}

__device__ __forceinline__ void calc_weights(const float* __restrict__ rcn_z,
                                             float cni, float* __restrict__ w) {
    float r[NREF], arg[NREF];
    float rmax = -1e30f, marg = -1e30f;
#pragma unroll
    for (int a = 0; a < NREF; a++) {
        r[a] = rcn_z[a];
        rmax = fmaxf(rmax, r[a]);
        float dc = r[a] - cni;
        arg[a] = (-4.0f * dc) * dc;
        if (r[a] >= 0.0f) marg = fmaxf(marg, arg[a]);
    }
    if (marg < EXC_CUT) {
#pragma unroll
        for (int a = 0; a < NREF; a++) w[a] = (r[a] == rmax) ? 1.0f : 0.0f;
    } else {
        float g[NREF], norm = 0.0f;
#pragma unroll
        for (int a = 0; a < NREF; a++) {
            float e = (r[a] >= 0.0f) ? expf(arg[a]) : 0.0f;
            g[a] = e;
            norm += e;
        }
        float inv = 1.0f / fmaxf(norm, 1e-30f);
#pragma unroll
        for (int a = 0; a < NREF; a++) w[a] = g[a] * inv;
    }
}

struct Params {
    const float *dist, *rcov, *rcn, *rc6, *r2r4, *s6p, *s8p, *a1p, *a2p;
    const int *Z, *idxi, *idxj;
    float *out;
    uint32_t *bcount;
    float *cn, *rcovA, *arec, *rc6pad;
    uint2 *recs;
    int n_pairs, n_atoms;
};

// ---------------------------------------------------------------------------
// The whole pipeline in one cooperative dispatch.
__global__ __launch_bounds__(256, 2) void d3_fused(Params p) {
    cg::grid_group grid = cg::this_grid();
    __shared__ union {
        struct { uint32_t hist[NB]; uint32_t run[NB]; } s1;            // 4 KB
        struct { float lrc[BSZ]; float acc[BSZ]; } s2;                 // 1 KB
        struct { float4 la0[BSZ]; float4 la1[BSZ]; float acc[BSZ]; } s4; // 4.5 KB
    } sh;
    const int T = NB * 256;
    const int gtid = blockIdx.x * 256 + (int)threadIdx.x;

    // ---- phase 0: init counters, per-atom rcov gather, rc6 tile repack ----
    if (gtid < NB) p.bcount[gtid] = 0;
    for (int i = gtid; i < p.n_atoms; i += T) p.rcovA[i] = p.rcov[p.Z[i]];
    for (int id = gtid; id < RC_TOTAL; id += T) {
        int tile = id >> 5, slot = id & 31;
        p.rc6pad[id] = (slot < 25) ? p.rc6[(size_t)tile * 25 + slot] : 0.0f;
    }
    grid.sync();

    // ---- phase 1: scatter pairs into fixed-stride buckets ----
    {
        int chunk = (p.n_pairs + NB - 1) / NB;
        int lo = blockIdx.x * chunk;
        int hi = min(lo + chunk, p.n_pairs);
        for (int t = threadIdx.x; t < NB; t += 256) sh.s1.hist[t] = 0;
        __syncthreads();
        for (int q = lo + (int)threadIdx.x; q < hi; q += 256) {
            if (p.dist[q] < 12.0f)
                atomicAdd(&sh.s1.hist[((uint32_t)p.idxi[q]) >> BSH], 1u);
        }
        __syncthreads();
        for (int t = threadIdx.x; t < NB; t += 256) {
            uint32_t h = sh.s1.hist[t];
            sh.s1.run[t] = h ? atomicAdd(&p.bcount[t], h) : 0u;
        }
        __syncthreads();
        for (int q = lo + (int)threadIdx.x; q < hi; q += 256) {
            float d = p.dist[q];
            if (d >= 12.0f) continue;                 // sw == 0: drop
            uint32_t i = (uint32_t)p.idxi[q];
            uint32_t b = i >> BSH;
            uint32_t pos = atomicAdd(&sh.s1.run[b], 1u);
            if (pos < (1u << CAPSH)) {
                uint32_t packed = ((uint32_t)p.idxj[q] & 0xFFFFu) |
                                  ((i & (BSZ - 1u)) << 16);
                p.recs[((size_t)b << CAPSH) + pos] =
                    make_uint2(__float_as_uint(d), packed);
            }
        }
    }
    grid.sync();

    // ---- phase 2: coordination numbers, LDS accumulation ----
    {
        int b = blockIdx.x;
        int base = b << BSH;
        for (int t = threadIdx.x; t < BSZ; t += 256) {
            int i = base + t;
            sh.s2.lrc[t] = (i < p.n_atoms) ? p.rcovA[i] : 0.0f;
            sh.s2.acc[t] = 0.0f;
        }
        __syncthreads();
        uint32_t n = min(p.bcount[b], 1u << CAPSH);
        const uint2* r0 = p.recs + ((size_t)b << CAPSH);
        for (uint32_t k = threadIdx.x; k < n; k += 256) {
            uint2 r = r0[k];
            float d = __uint_as_float(r.x);
            int j  = r.y & 0xFFFF;
            int il = r.y >> 16;
            float rij = sh.s2.lrc[il] + p.rcovA[j];
            float sw = switch_fn(d);
            atomicAdd(&sh.s2.acc[il], sw / (1.0f + expf(-16.0f * (rij / d - 1.0f))));
        }
        __syncthreads();
        for (int t = threadIdx.x; t < BSZ; t += 256) {
            int i = base + t;
            if (i < p.n_atoms) p.cn[i] = sh.s2.acc[t];
        }
    }
    grid.sync();

    // ---- phase 3: per-atom Gaussian weights -> 32B records ----
    for (int i = gtid; i < p.n_atoms; i += T) {
        int z = p.Z[i];
        float w[NREF];
        calc_weights(p.rcn + (size_t)z * NREF, p.cn[i], w);
        float4 v0 = make_float4(w[0], w[1], w[2], w[3]);
        float4 v1 = make_float4(w[4], p.r2r4[z], __int_as_float(z), 0.0f);
        float4* dst = (float4*)(p.arec + (size_t)i * 8);
        dst[0] = v0;
        dst[1] = v1;
    }
    grid.sync();

    // ---- phase 4: pair energies, LDS accumulation, non-atomic store ----
    {
        int b = blockIdx.x;
        int base = b << BSH;
        for (int t = threadIdx.x; t < BSZ; t += 256) {
            int i = min(base + t, p.n_atoms - 1);
            const float4* A = (const float4*)(p.arec + (size_t)i * 8);
            sh.s4.la0[t] = A[0];
            sh.s4.la1[t] = A[1];
            sh.s4.acc[t] = 0.0f;
        }
        __syncthreads();
        float s6 = p.s6p[0], s8 = p.s8p[0], a1 = p.a1p[0], a2 = p.a2p[0];
        uint32_t n = min(p.bcount[b], 1u << CAPSH);
        const uint2* r0 = p.recs + ((size_t)b << CAPSH);
        for (uint32_t k = threadIdx.x; k < n; k += 256) {
            uint2 r = r0[k];
            float d = __uint_as_float(r.x);
            int j  = r.y & 0xFFFF;
            int il = r.y >> 16;
            float4 ai0 = sh.s4.la0[il];
            float4 ai1 = sh.s4.la1[il];
            const float4* Aj = (const float4*)(p.arec + (size_t)j * 8);
            float4 aj0 = Aj[0];
            float4 aj1 = Aj[1];
            float wi[NREF] = {ai0.x, ai0.y, ai0.z, ai0.w, ai1.x};
            float wj[NREF] = {aj0.x, aj0.y, aj0.z, aj0.w, aj1.x};
            int zi = __float_as_int(ai1.z);
            int zj = __float_as_int(aj1.z);

            const float4* T4 = (const float4*)(p.rc6pad + (size_t)(zi * MAXZ + zj) * 32);
            float tt[25];
#pragma unroll
            for (int kk = 0; kk < 6; kk++) {
                float4 t = T4[kk];
                tt[4 * kk + 0] = t.x;
                if (4 * kk + 1 < 25) tt[4 * kk + 1] = t.y;
                if (4 * kk + 2 < 25) tt[4 * kk + 2] = t.z;
                if (4 * kk + 3 < 25) tt[4 * kk + 3] = t.w;
            }
            tt[24] = ((const float*)T4)[24];

            float c6 = 0.0f;
#pragma unroll
            for (int a = 0; a < NREF; a++) {
                float s = 0.0f;
#pragma unroll
                for (int bb = 0; bb < NREF; bb++) s = fmaf(wj[bb], tt[a * NREF + bb], s);
                c6 = fmaf(wi[a], s, c6);
            }

            float qq = 3.0f * ai1.y * aj1.y;
            float rr = a1 * sqrtf(qq) + a2;
            float d2 = d * d;
            float d6 = d2 * d2 * d2;
            float d8 = d6 * d2;
            float rr2 = rr * rr;
            float rr6 = rr2 * rr2 * rr2;
            float rr8 = rr6 * rr2;
            float sw = switch_fn(d);

            float e = -0.5f * (s6 * c6 / (d6 + rr6) + s8 * qq * c6 / (d8 + rr8)) * sw;
            atomicAdd(&sh.s4.acc[il], e);
        }
        __syncthreads();
        for (int t = threadIdx.x; t < BSZ; t += 256) {
            int i = base + t;
            if (i < p.n_atoms) p.out[i] = sh.s4.acc[t];
        }
    }
}

// ===========================================================================
// Fallback path (R6-proven multi-kernel sorted pipeline).
// ===========================================================================
__global__ __launch_bounds__(256) void prep_rcov(const float* __restrict__ rcov,
                                                 const int* __restrict__ Z,
                                                 float* __restrict__ rcovA,
                                                 int n_atoms) {
    int i = blockIdx.x * blockDim.x + threadIdx.x;
    if (i >= n_atoms) return;
    rcovA[i] = rcov[Z[i]];
}

__global__ __launch_bounds__(256) void repack_rc6(const float* __restrict__ rc6,
                                                  float* __restrict__ rc6pad,
                                                  int total) {
    int id = blockIdx.x * blockDim.x + threadIdx.x;
    if (id >= total) return;
    int tile = id >> 5;
    int slot = id & 31;
    rc6pad[id] = (slot < 25) ? rc6[(size_t)tile * 25 + slot] : 0.0f;
}

__global__ __launch_bounds__(1024) void scatter_pairs(const float* __restrict__ dist,
                                                      const int* __restrict__ idx_i,
                                                      const int* __restrict__ idx_j,
                                                      uint32_t* __restrict__ bcount,
                                                      uint2* __restrict__ recs,
                                                      int n_pairs, int chunk) {
    __shared__ uint32_t hist[NB];
    __shared__ uint32_t run[NB];
    for (int t = threadIdx.x; t < NB; t += 1024) hist[t] = 0;
    __syncthreads();
    int lo = blockIdx.x * chunk;
    int hi = min(lo + chunk, n_pairs);
    for (int q = lo + (int)threadIdx.x; q < hi; q += 1024) {
        float d = dist[q];
        if (d < 12.0f) atomicAdd(&hist[((uint32_t)idx_i[q]) >> BSH], 1u);
    }
    __syncthreads();
    for (int t = threadIdx.x; t < NB; t += 1024) {
        uint32_t h = hist[t];
        run[t] = h ? atomicAdd(&bcount[t], h) : 0u;
    }
    __syncthreads();
    for (int q = lo + (int)threadIdx.x; q < hi; q += 1024) {
        float d = dist[q];
        if (d >= 12.0f) continue;
        uint32_t i = (uint32_t)idx_i[q];
        uint32_t b = i >> BSH;
        uint32_t pos = atomicAdd(&run[b], 1u);
        if (pos < (1u << CAPSH)) {
            uint32_t packed = ((uint32_t)idx_j[q] & 0xFFFFu) | ((i & (BSZ - 1u)) << 16);
            recs[((size_t)b << CAPSH) + pos] = make_uint2(__float_as_uint(d), packed);
        }
    }
}

__global__ __launch_bounds__(256) void cn_bucket(const uint2* __restrict__ recs,
                                                 const uint32_t* __restrict__ bcount,
                                                 const float* __restrict__ rcovA,
                                                 float* __restrict__ cn,
                                                 int n_atoms) {
    __shared__ float lrc[BSZ];
    __shared__ float acc[BSZ];
    int b = blockIdx.x;
    int base = b << BSH;
    for (int t = threadIdx.x; t < BSZ; t += 256) {
        int i = base + t;
        lrc[t] = (i < n_atoms) ? rcovA[i] : 0.0f;
        acc[t] = 0.0f;
    }
    __syncthreads();
    uint32_t n = min(bcount[b], 1u << CAPSH);
    const uint2* r0 = recs + ((size_t)b << CAPSH);
    for (uint32_t k = threadIdx.x; k < n; k += 256) {
        uint2 r = r0[k];
        float d = __uint_as_float(r.x);
        int j  = r.y & 0xFFFF;
        int il = r.y >> 16;
        float rij = lrc[il] + rcovA[j];
        float sw = switch_fn(d);
        atomicAdd(&acc[il], sw / (1.0f + expf(-16.0f * (rij / d - 1.0f))));
    }
    __syncthreads();
    for (int t = threadIdx.x; t < BSZ; t += 256) {
        int i = base + t;
        if (i < n_atoms) cn[i] = acc[t];
    }
}

__global__ __launch_bounds__(256) void atom_weights(const float* __restrict__ rcn,
                                                    const float* __restrict__ r2r4,
                                                    const int* __restrict__ Z,
                                                    const float* __restrict__ cn,
                                                    float* __restrict__ arec,
                                                    int n_atoms) {
    int i = blockIdx.x * blockDim.x + threadIdx.x;
    if (i >= n_atoms) return;
    int z = Z[i];
    float w[NREF];
    calc_weights(rcn + (size_t)z * NREF, cn[i], w);
    float4 v0 = make_float4(w[0], w[1], w[2], w[3]);
    float4 v1 = make_float4(w[4], r2r4[z], __int_as_float(z), 0.0f);
    float4* dst = (float4*)(arec + (size_t)i * 8);
    dst[0] = v0;
    dst[1] = v1;
}

__global__ __launch_bounds__(256) void energy_bucket(const uint2* __restrict__ recs,
                                                     const uint32_t* __restrict__ bcount,
                                                     const float* __restrict__ arec,
                                                     const float* __restrict__ rc6pad,
                                                     const float* __restrict__ s6p,
                                                     const float* __restrict__ s8p,
                                                     const float* __restrict__ a1p,
                                                     const float* __restrict__ a2p,
                                                     float* __restrict__ eout,
                                                     int n_atoms) {
    __shared__ float4 la0[BSZ];
    __shared__ float4 la1[BSZ];
    __shared__ float  acc[BSZ];
    int b = blockIdx.x;
    int base = b << BSH;
    for (int t = threadIdx.x; t < BSZ; t += 256) {
        int i = min(base + t, n_atoms - 1);
        const float4* A = (const float4*)(arec + (size_t)i * 8);
        la0[t] = A[0];
        la1[t] = A[1];
        acc[t] = 0.0f;
    }
    __syncthreads();
    float s6 = s6p[0], s8 = s8p[0], a1 = a1p[0], a2 = a2p[0];
    uint32_t n = min(bcount[b], 1u << CAPSH);
    const uint2* r0 = recs + ((size_t)b << CAPSH);
    for (uint32_t k = threadIdx.x; k < n; k += 256) {
        uint2 r = r0[k];
        float d = __uint_as_float(r.x);
        int j  = r.y & 0xFFFF;
        int il = r.y >> 16;
        float4 ai0 = la0[il];
        float4 ai1 = la1[il];
        const float4* Aj = (const float4*)(arec + (size_t)j * 8);
        float4 aj0 = Aj[0];
        float4 aj1 = Aj[1];
        float wi[NREF] = {ai0.x, ai0.y, ai0.z, ai0.w, ai1.x};
        float wj[NREF] = {aj0.x, aj0.y, aj0.z, aj0.w, aj1.x};
        int zi = __float_as_int(ai1.z);
        int zj = __float_as_int(aj1.z);
        const float4* T4 = (const float4*)(rc6pad + (size_t)(zi * MAXZ + zj) * 32);
        float tt[25];
#pragma unroll
        for (int kk = 0; kk < 6; kk++) {
            float4 t = T4[kk];
            tt[4 * kk + 0] = t.x;
            if (4 * kk + 1 < 25) tt[4 * kk + 1] = t.y;
            if (4 * kk + 2 < 25) tt[4 * kk + 2] = t.z;
            if (4 * kk + 3 < 25) tt[4 * kk + 3] = t.w;
        }
        tt[24] = ((const float*)T4)[24];
        float c6 = 0.0f;
#pragma unroll
        for (int a = 0; a < NREF; a++) {
            float s = 0.0f;
#pragma unroll
            for (int bb = 0; bb < NREF; bb++) s = fmaf(wj[bb], tt[a * NREF + bb], s);
            c6 = fmaf(wi[a], s, c6);
        }
        float qq = 3.0f * ai1.y * aj1.y;
        float rr = a1 * sqrtf(qq) + a2;
        float d2 = d * d;
        float d6 = d2 * d2 * d2;
        float d8 = d6 * d2;
        float rr2 = rr * rr;
        float rr6 = rr2 * rr2 * rr2;
        float rr8 = rr6 * rr2;
        float sw = switch_fn(d);
        float e = -0.5f * (s6 * c6 / (d6 + rr6) + s8 * qq * c6 / (d8 + rr8)) * sw;
        atomicAdd(&acc[il], e);
    }
    __syncthreads();
    for (int t = threadIdx.x; t < BSZ; t += 256) {
        int i = base + t;
        if (i < n_atoms) eout[i] = acc[t];
    }
}

// ---------------------------------------------------------------------------
extern "C" void kernel_launch(void* const* d_in, const int* in_sizes, int n_in,
                              void* d_out, int out_size, void* d_ws, size_t ws_size,
                              hipStream_t stream) {
    const float* dist = (const float*)d_in[0];
    const float* rcov = (const float*)d_in[1];
    const float* rcn  = (const float*)d_in[2];
    const float* rc6  = (const float*)d_in[3];
    const float* r2r4 = (const float*)d_in[4];
    const float* s6p  = (const float*)d_in[5];
    const float* s8p  = (const float*)d_in[6];
    const float* a1p  = (const float*)d_in[7];
    const float* a2p  = (const float*)d_in[8];
    const int* Z    = (const int*)d_in[9];
    const int* idxi = (const int*)d_in[10];
    const int* idxj = (const int*)d_in[11];
    float* out = (float*)d_out;

    int n_pairs = in_sizes[0];
    int n_atoms = in_sizes[9];

    // workspace layout (shared by fused + fallback paths)
    char* ws = (char*)d_ws;
    size_t o_bcount = 0;                                   // NB u32 (pad 4096)
    size_t o_cn     = 4096;
    size_t o_rcovA  = o_cn + (size_t)n_atoms * 4;
    size_t o_arec   = o_rcovA + (size_t)n_atoms * 4;
    size_t o_rc6    = o_arec + (size_t)n_atoms * 32;
    size_t o_recs   = (o_rc6 + (size_t)RC_TOTAL * 4 + 255) & ~(size_t)255;
    size_t need     = o_recs + ((size_t)NB << CAPSH) * 8;

    uint32_t* bcount = (uint32_t*)(ws + o_bcount);
    float* cn     = (float*)(ws + o_cn);
    float* rcovA  = (float*)(ws + o_rcovA);
    float* arec   = (float*)(ws + o_arec);
    float* rcpad  = (float*)(ws + o_rc6);
    uint2* recs   = (uint2*)(ws + o_recs);

    bool ok = (ws_size >= need) && (n_atoms <= NB * BSZ) && (n_atoms <= 65536);
    if (ok) {
        Params prm;
        prm.dist = dist; prm.rcov = rcov; prm.rcn = rcn; prm.rc6 = rc6;
        prm.r2r4 = r2r4; prm.s6p = s6p; prm.s8p = s8p; prm.a1p = a1p;
        prm.a2p = a2p; prm.Z = Z; prm.idxi = idxi; prm.idxj = idxj;
        prm.out = out; prm.bcount = bcount; prm.cn = cn; prm.rcovA = rcovA;
        prm.arec = arec; prm.rc6pad = rcpad; prm.recs = recs;
        prm.n_pairs = n_pairs; prm.n_atoms = n_atoms;
        void* args[] = {&prm};
        hipError_t e = hipLaunchCooperativeKernel((const void*)d3_fused,
                                                  dim3(NB), dim3(256),
                                                  args, 0, stream);
        if (e == hipSuccess) return;
        (void)hipGetLastError();   // clear; fall through to multi-kernel path
    }

    // fallback: R6-proven sorted multi-kernel pipeline
    int agrid = (n_atoms + 255) / 256;
    hipMemsetAsync(bcount, 0, NB * 4, stream);
    prep_rcov<<<agrid, 256, 0, stream>>>(rcov, Z, rcovA, n_atoms);
    repack_rc6<<<(RC_TOTAL + 255) / 256, 256, 0, stream>>>(rc6, rcpad, RC_TOTAL);
    int sblocks = 256;
    int chunk = (n_pairs + sblocks - 1) / sblocks;
    scatter_pairs<<<sblocks, 1024, 0, stream>>>(dist, idxi, idxj, bcount, recs,
                                                n_pairs, chunk);
    cn_bucket<<<NB, 256, 0, stream>>>(recs, bcount, rcovA, cn, n_atoms);
    atom_weights<<<agrid, 256, 0, stream>>>(rcn, r2r4, Z, cn, arec, n_atoms);
    energy_bucket<<<NB, 256, 0, stream>>>(recs, bcount, arec, rcpad,
                                          s6p, s8p, a1p, a2p, out, n_atoms);
}

// Round 8
// 172.011 us; speedup vs baseline: 2.5912x; 2.5912x over previous
//
#include <hip/hip_runtime.h>
#include <stdint.h>

// D3 dispersion on MI355X (gfx950).
// R7 post-mortem: cooperative fusion capped occupancy at 2 blocks/CU (24%)
// and regressed 183->445us. R8: proven multi-kernel bucket pipeline, tuned:
//   - fixed-stride buckets (no count+scan), NB=1024 (64 atoms/bucket) so the
//     latency-bound bucket kernels run 4 blocks/CU (~16 waves/CU),
//   - prep_rcov + rc6 repack folded into scatter's prologue (5 dispatches),
//   - zero global fp32 atomics (LDS accumulation, coalesced stores).
// Reference semantics (established R2-R5): fp32 storage; np reference is fp32
// with FTZ in exp -> exceptional one-hot branch iff every masked gaussian
// arg < ln(2^-126) = -87.33654.

typedef unsigned short u16;
#define MAXZ 95
#define NREF 5
#define EXC_CUT -87.33654f
#define NB    1024     // buckets
#define BSH   6        // log2 atoms per bucket
#define BSZ   64       // atoms per bucket
#define CAPSH 12       // bucket capacity 4096 (mean ~1865, sigma ~43: +52 sigma)
#define RC_TOTAL (MAXZ * MAXZ * 32)

__device__ __forceinline__ float switch_fn(float d) {
    if (d < 10.0f) return 1.0f;
    float x = (12.0f - d) * 0.5f;
    return ((6.0f * x - 15.0f) * x + 10.0f) * x * x * x;
}

__device__ __forceinline__ void calc_weights(const float* __restrict__ rcn_z,
                                             float cni, float* __restrict__ w) {
    float r[NREF], arg[NREF];
    float rmax = -1e30f, marg = -1e30f;
#pragma unroll
    for (int a = 0; a < NREF; a++) {
        r[a] = rcn_z[a];
        rmax = fmaxf(rmax, r[a]);
        float dc = r[a] - cni;
        arg[a] = (-4.0f * dc) * dc;
        if (r[a] >= 0.0f) marg = fmaxf(marg, arg[a]);
    }
    if (marg < EXC_CUT) {
#pragma unroll
        for (int a = 0; a < NREF; a++) w[a] = (r[a] == rmax) ? 1.0f : 0.0f;
    } else {
        float g[NREF], norm = 0.0f;
#pragma unroll
        for (int a = 0; a < NREF; a++) {
            float e = (r[a] >= 0.0f) ? expf(arg[a]) : 0.0f;
            g[a] = e;
            norm += e;
        }
        float inv = 1.0f / fmaxf(norm, 1e-30f);
#pragma unroll
        for (int a = 0; a < NREF; a++) w[a] = g[a] * inv;
    }
}

// ---------------------------------------------------------------------------
// Scatter pairs into fixed-stride buckets; prologue also fills rcovA (used by
// cn_bucket) and the padded rc6 tiles (used by energy_bucket).
__global__ __launch_bounds__(1024) void scatter_pairs(const float* __restrict__ dist,
                                                      const int* __restrict__ idx_i,
                                                      const int* __restrict__ idx_j,
                                                      const int* __restrict__ Z,
                                                      const float* __restrict__ rcov,
                                                      const float* __restrict__ rc6,
                                                      float* __restrict__ rcovA,
                                                      float* __restrict__ rc6pad,
                                                      uint32_t* __restrict__ bcount,
                                                      uint2* __restrict__ recs,
                                                      int n_pairs, int n_atoms,
                                                      int chunk) {
    __shared__ uint32_t hist[NB];
    __shared__ uint32_t run[NB];

    // prologue: per-atom rcov gather + rc6 tile repack (grid-stride)
    int g = blockIdx.x * 1024 + (int)threadIdx.x;
    int T = gridDim.x * 1024;
    for (int i = g; i < n_atoms; i += T) rcovA[i] = rcov[Z[i]];
    for (int id = g; id < RC_TOTAL; id += T) {
        int tile = id >> 5, slot = id & 31;
        rc6pad[id] = (slot < 25) ? rc6[(size_t)tile * 25 + slot] : 0.0f;
    }

    for (int t = threadIdx.x; t < NB; t += 1024) hist[t] = 0;
    __syncthreads();
    int lo = blockIdx.x * chunk;
    int hi = min(lo + chunk, n_pairs);
    for (int q = lo + (int)threadIdx.x; q < hi; q += 1024) {
        if (dist[q] < 12.0f)
            atomicAdd(&hist[((uint32_t)idx_i[q]) >> BSH], 1u);
    }
    __syncthreads();
    for (int t = threadIdx.x; t < NB; t += 1024) {
        uint32_t h = hist[t];
        run[t] = h ? atomicAdd(&bcount[t], h) : 0u;
    }
    __syncthreads();
    for (int q = lo + (int)threadIdx.x; q < hi; q += 1024) {
        float d = dist[q];
        if (d >= 12.0f) continue;                  // sw == 0: drop
        uint32_t i = (uint32_t)idx_i[q];
        uint32_t b = i >> BSH;
        uint32_t pos = atomicAdd(&run[b], 1u);
        if (pos < (1u << CAPSH)) {
            uint32_t packed = ((uint32_t)idx_j[q] & 0xFFFFu) |
                              ((i & (BSZ - 1u)) << 16);
            recs[((size_t)b << CAPSH) + pos] = make_uint2(__float_as_uint(d), packed);
        }
    }
}

// ---------------------------------------------------------------------------
// CN phase: one block per bucket, LDS accumulation, coalesced store.
__global__ __launch_bounds__(256) void cn_bucket(const uint2* __restrict__ recs,
                                                 const uint32_t* __restrict__ bcount,
                                                 const float* __restrict__ rcovA,
                                                 float* __restrict__ cn,
                                                 int n_atoms) {
    __shared__ float lrc[BSZ];
    __shared__ float acc[BSZ];
    int b = blockIdx.x;
    int base = b << BSH;
    if (threadIdx.x < BSZ) {
        int i = base + (int)threadIdx.x;
        lrc[threadIdx.x] = (i < n_atoms) ? rcovA[i] : 0.0f;
        acc[threadIdx.x] = 0.0f;
    }
    __syncthreads();
    uint32_t n = min(bcount[b], 1u << CAPSH);
    const uint2* r0 = recs + ((size_t)b << CAPSH);
    for (uint32_t k = threadIdx.x; k < n; k += 256) {
        uint2 r = r0[k];
        float d = __uint_as_float(r.x);
        int j  = r.y & 0xFFFF;
        int il = r.y >> 16;
        float rij = lrc[il] + rcovA[j];
        float sw = switch_fn(d);
        atomicAdd(&acc[il], sw / (1.0f + expf(-16.0f * (rij / d - 1.0f))));
    }
    __syncthreads();
    if (threadIdx.x < BSZ) {
        int i = base + (int)threadIdx.x;
        if (i < n_atoms) cn[i] = acc[threadIdx.x];
    }
}

// ---------------------------------------------------------------------------
// Per-atom record: {w0..w4, r2r4[z], z_bits, 0} = 32 B (one cache line).
__global__ __launch_bounds__(256) void atom_weights(const float* __restrict__ rcn,
                                                    const float* __restrict__ r2r4,
                                                    const int* __restrict__ Z,
                                                    const float* __restrict__ cn,
                                                    float* __restrict__ arec,
                                                    int n_atoms) {
    int i = blockIdx.x * blockDim.x + threadIdx.x;
    if (i >= n_atoms) return;
    int z = Z[i];
    float w[NREF];
    calc_weights(rcn + (size_t)z * NREF, cn[i], w);
    float4 v0 = make_float4(w[0], w[1], w[2], w[3]);
    float4 v1 = make_float4(w[4], r2r4[z], __int_as_float(z), 0.0f);
    float4* dst = (float4*)(arec + (size_t)i * 8);
    dst[0] = v0;
    dst[1] = v1;
}

// ---------------------------------------------------------------------------
// Energy phase: one block per bucket; i-side from LDS, j-side 2x float4 L2
// gather, rc6 two-line gather; LDS accumulation, coalesced store.
__global__ __launch_bounds__(256) void energy_bucket(const uint2* __restrict__ recs,
                                                     const uint32_t* __restrict__ bcount,
                                                     const float* __restrict__ arec,
                                                     const float* __restrict__ rc6pad,
                                                     const float* __restrict__ s6p,
                                                     const float* __restrict__ s8p,
                                                     const float* __restrict__ a1p,
                                                     const float* __restrict__ a2p,
                                                     float* __restrict__ eout,
                                                     int n_atoms) {
    __shared__ float4 la0[BSZ];
    __shared__ float4 la1[BSZ];
    __shared__ float  acc[BSZ];
    int b = blockIdx.x;
    int base = b << BSH;
    if (threadIdx.x < BSZ) {
        int i = min(base + (int)threadIdx.x, n_atoms - 1);
        const float4* A = (const float4*)(arec + (size_t)i * 8);
        la0[threadIdx.x] = A[0];
        la1[threadIdx.x] = A[1];
        acc[threadIdx.x] = 0.0f;
    }
    __syncthreads();
    float s6 = s6p[0], s8 = s8p[0], a1 = a1p[0], a2 = a2p[0];
    uint32_t n = min(bcount[b], 1u << CAPSH);
    const uint2* r0 = recs + ((size_t)b << CAPSH);
    for (uint32_t k = threadIdx.x; k < n; k += 256) {
        uint2 r = r0[k];
        float d = __uint_as_float(r.x);
        int j  = r.y & 0xFFFF;
        int il = r.y >> 16;
        float4 ai0 = la0[il];
        float4 ai1 = la1[il];
        const float4* Aj = (const float4*)(arec + (size_t)j * 8);
        float4 aj0 = Aj[0];
        float4 aj1 = Aj[1];
        float wi[NREF] = {ai0.x, ai0.y, ai0.z, ai0.w, ai1.x};
        float wj[NREF] = {aj0.x, aj0.y, aj0.z, aj0.w, aj1.x};
        int zi = __float_as_int(ai1.z);
        int zj = __float_as_int(aj1.z);

        const float4* T4 = (const float4*)(rc6pad + (size_t)(zi * MAXZ + zj) * 32);
        float tt[25];
#pragma unroll
        for (int kk = 0; kk < 6; kk++) {
            float4 t = T4[kk];
            tt[4 * kk + 0] = t.x;
            if (4 * kk + 1 < 25) tt[4 * kk + 1] = t.y;
            if (4 * kk + 2 < 25) tt[4 * kk + 2] = t.z;
            if (4 * kk + 3 < 25) tt[4 * kk + 3] = t.w;
        }
        tt[24] = ((const float*)T4)[24];

        float c6 = 0.0f;
#pragma unroll
        for (int a = 0; a < NREF; a++) {
            float s = 0.0f;
#pragma unroll
            for (int bb = 0; bb < NREF; bb++) s = fmaf(wj[bb], tt[a * NREF + bb], s);
            c6 = fmaf(wi[a], s, c6);
        }

        float qq = 3.0f * ai1.y * aj1.y;
        float rr = a1 * sqrtf(qq) + a2;
        float d2 = d * d;
        float d6 = d2 * d2 * d2;
        float d8 = d6 * d2;
        float rr2 = rr * rr;
        float rr6 = rr2 * rr2 * rr2;
        float rr8 = rr6 * rr2;
        float sw = switch_fn(d);

        float e = -0.5f * (s6 * c6 / (d6 + rr6) + s8 * qq * c6 / (d8 + rr8)) * sw;
        atomicAdd(&acc[il], e);
    }
    __syncthreads();
    if (threadIdx.x < BSZ) {
        int i = base + (int)threadIdx.x;
        if (i < n_atoms) eout[i] = acc[threadIdx.x];
    }
}

// ---------------------------------------------------------------------------
// Slim fallback (small workspace): R5-style global-atomic path.
__global__ __launch_bounds__(256) void pair_cn_slim(const float* __restrict__ dist,
                                                    const float* __restrict__ rcov,
                                                    const int* __restrict__ Z,
                                                    const int* __restrict__ idx_i,
                                                    const int* __restrict__ idx_j,
                                                    float* __restrict__ cn,
                                                    int n_pairs) {
    int p = blockIdx.x * blockDim.x + threadIdx.x;
    if (p >= n_pairs) return;
    float d = dist[p];
    if (d >= 12.0f) return;
    float rij = rcov[Z[idx_i[p]]] + rcov[Z[idx_j[p]]];
    float sw = switch_fn(d);
    atomicAdd(&cn[idx_i[p]], sw / (1.0f + expf(-16.0f * (rij / d - 1.0f))));
}

__global__ __launch_bounds__(256) void pair_energy_slim(const float* __restrict__ dist,
                                                        const int* __restrict__ Z,
                                                        const int* __restrict__ idx_i,
                                                        const int* __restrict__ idx_j,
                                                        const float* __restrict__ cn,
                                                        const float* __restrict__ rcn,
                                                        const float* __restrict__ r2r4,
                                                        const float* __restrict__ rc6,
                                                        const float* __restrict__ s6p,
                                                        const float* __restrict__ s8p,
                                                        const float* __restrict__ a1p,
                                                        const float* __restrict__ a2p,
                                                        float* __restrict__ eout,
                                                        int n_pairs) {
    int p = blockIdx.x * blockDim.x + threadIdx.x;
    if (p >= n_pairs) return;
    float d = dist[p];
    if (d >= 12.0f) return;
    int i = idx_i[p], j = idx_j[p];
    int zi = Z[i], zj = Z[j];
    float wi[NREF], wj[NREF];
    calc_weights(rcn + (size_t)zi * NREF, cn[i], wi);
    calc_weights(rcn + (size_t)zj * NREF, cn[j], wj);
    const float* T = rc6 + (size_t)(zi * MAXZ + zj) * 25;
    float c6 = 0.0f;
#pragma unroll
    for (int a = 0; a < NREF; a++) {
        float s = 0.0f;
#pragma unroll
        for (int bb = 0; bb < NREF; bb++) s = fmaf(wj[bb], T[a * NREF + bb], s);
        c6 = fmaf(wi[a], s, c6);
    }
    float qq = 3.0f * r2r4[zi] * r2r4[zj];
    float rr = a1p[0] * sqrtf(qq) + a2p[0];
    float d2 = d * d;
    float d6 = d2 * d2 * d2;
    float d8 = d6 * d2;
    float rr2 = rr * rr;
    float rr6 = rr2 * rr2 * rr2;
    float rr8 = rr6 * rr2;
    float sw = switch_fn(d);
    float e = -0.5f * (s6p[0] * c6 / (d6 + rr6) + s8p[0] * qq * c6 / (d8 + rr8)) * sw;
    atomicAdd(&eout[i], e);
}

// ---------------------------------------------------------------------------
extern "C" void kernel_launch(void* const* d_in, const int* in_sizes, int n_in,
                              void* d_out, int out_size, void* d_ws, size_t ws_size,
                              hipStream_t stream) {
    const float* dist = (const float*)d_in[0];
    const float* rcov = (const float*)d_in[1];
    const float* rcn  = (const float*)d_in[2];
    const float* rc6  = (const float*)d_in[3];
    const float* r2r4 = (const float*)d_in[4];
    const float* s6p  = (const float*)d_in[5];
    const float* s8p  = (const float*)d_in[6];
    const float* a1p  = (const float*)d_in[7];
    const float* a2p  = (const float*)d_in[8];
    const int* Z    = (const int*)d_in[9];
    const int* idxi = (const int*)d_in[10];
    const int* idxj = (const int*)d_in[11];
    float* out = (float*)d_out;

    int n_pairs = in_sizes[0];
    int n_atoms = in_sizes[9];
    int agrid = (n_atoms + 255) / 256;

    char* ws = (char*)d_ws;
    size_t o_bcount = 0;                                       // NB u32
    size_t o_cn     = (size_t)NB * 4;
    size_t o_rcovA  = o_cn + (size_t)n_atoms * 4;
    size_t o_arec   = (o_rcovA + (size_t)n_atoms * 4 + 31) & ~(size_t)31;
    size_t o_rc6    = o_arec + (size_t)n_atoms * 32;
    size_t o_recs   = (o_rc6 + (size_t)RC_TOTAL * 4 + 255) & ~(size_t)255;
    size_t need     = o_recs + ((size_t)NB << CAPSH) * 8;

    uint32_t* bcount = (uint32_t*)(ws + o_bcount);
    float* cn     = (float*)(ws + o_cn);
    float* rcovA  = (float*)(ws + o_rcovA);
    float* arec   = (float*)(ws + o_arec);
    float* rcpad  = (float*)(ws + o_rc6);
    uint2* recs   = (uint2*)(ws + o_recs);

    if (ws_size >= need && n_atoms <= NB * BSZ) {
        hipMemsetAsync(bcount, 0, NB * 4, stream);
        int sblocks = 256;
        int chunk = (n_pairs + sblocks - 1) / sblocks;
        scatter_pairs<<<sblocks, 1024, 0, stream>>>(dist, idxi, idxj, Z, rcov, rc6,
                                                    rcovA, rcpad, bcount, recs,
                                                    n_pairs, n_atoms, chunk);
        cn_bucket<<<NB, 256, 0, stream>>>(recs, bcount, rcovA, cn, n_atoms);
        atom_weights<<<agrid, 256, 0, stream>>>(rcn, r2r4, Z, cn, arec, n_atoms);
        energy_bucket<<<NB, 256, 0, stream>>>(recs, bcount, arec, rcpad,
                                              s6p, s8p, a1p, a2p, out, n_atoms);
    } else {
        int pgrid = (n_pairs + 255) / 256;
        hipMemsetAsync(out, 0, (size_t)n_atoms * 4, stream);
        hipMemsetAsync(cn, 0, (size_t)n_atoms * 4, stream);
        pair_cn_slim<<<pgrid, 256, 0, stream>>>(dist, rcov, Z, idxi, idxj, cn, n_pairs);
        pair_energy_slim<<<pgrid, 256, 0, stream>>>(dist, Z, idxi, idxj, cn, rcn, r2r4,
                                                    rc6, s6p, s8p, a1p, a2p, out, n_pairs);
    }
}